// Round 1
// baseline (153.500 us; speedup 1.0000x reference)
//
#include <hip/hip_runtime.h>
#include <hip/hip_bf16.h>

// Problem dims
#define X_B 8
#define X_C 64
#define X_H 64
#define X_W 64
#define X_S 12
// x index: (((b*64 + c)*64 + h)*64 + w)*12 + t
// h-row stride = 768 floats, channel stride = 49152 floats

// Scratch layout inside d_out (floats) — consumed before final output overwrites it:
//   [0,1600)                : Weff[c'*25 + tap]
//   [4096, 4096+16*393216)  : partial A_k per channel-group q, layout ((b*64+h)*64+w)*12+t
#define WEFF_OFF 0
#define PART_OFF 4096
#define PART_SZ  393216   // 8*64*64*12
// d_ws: p[((b*64+h)*64+w)*12 + t]  (393216 floats = 1.57 MB)

// ---------------------------------------------------------------------------
// K1: fold 1x1-conv (key half of w1) into the 5x5 conv weights.
// Weff[c'][tap] = sum_c w2[0, 64+c, dh, dw] * w1[64+c, c']
__global__ __launch_bounds__(256) void k_prep(const float* __restrict__ w1,
                                              const float* __restrict__ w2,
                                              float* __restrict__ weff) {
    int idx = blockIdx.x * 256 + threadIdx.x;
    if (idx >= 64 * 25) return;
    int cp = idx / 25, tap = idx % 25;
    float s = 0.f;
    for (int c = 0; c < 64; ++c)
        s = fmaf(w2[(64 + c) * 25 + tap], w1[(64 + c) * 64 + cp], s);
    weff[cp * 25 + tap] = s;
}

// ---------------------------------------------------------------------------
// K2: direct fused 5x5x64 conv on x producing partial A_k (bias dropped: it is
// t-independent and cancels in the softmax over t).
// Grid: 1536 blocks = 8 b * 4 h-strips * 3 t-groups * 16 channel-groups.
// Block: 128 threads = 64 w-lanes * 2 row-halves; each thread owns 8 output
// rows * 4 t -> 32 accumulators; loads are float4 (4 t), lane=w => coalesced.
__global__ __launch_bounds__(128) void k_conv(const float* __restrict__ x,
                                              const float* __restrict__ weff,
                                              float* __restrict__ part) {
    const int bid   = blockIdx.x;
    const int b     = bid & 7;
    const int strip = (bid >> 3) & 3;
    const int tg    = (bid >> 5) % 3;
    const int q     = bid / 96;            // 0..15 -> channels q*4 .. q*4+3

    const int w   = threadIdx.x & 63;
    const int hq  = threadIdx.x >> 6;      // 0..1
    const int htb = strip * 16 + hq * 8;   // this thread's output rows htb..htb+7

    float acc[8][4];
#pragma unroll
    for (int o = 0; o < 8; ++o)
#pragma unroll
        for (int j = 0; j < 4; ++j) acc[o][j] = 0.f;

    for (int ci = 0; ci < 4; ++ci) {
        const int c = q * 4 + ci;
        const float* wp = weff + c * 25;   // uniform -> scalar loads
        float wgt[25];
#pragma unroll
        for (int k = 0; k < 25; ++k) wgt[k] = wp[k];

        const float* xc = x + (size_t)(b * 64 + c) * 49152 + tg * 4;
#pragma unroll
        for (int rr = 0; rr < 12; ++rr) {          // input rows htb-2 .. htb+9
            const int r = htb - 2 + rr;
            if (r < 0 || r >= 64) continue;        // wave-uniform skip
            const float* xr = xc + r * 768;
#pragma unroll
            for (int dw = 0; dw < 5; ++dw) {
                const int wc = w + dw - 2;
                const bool ok = ((unsigned)wc < 64u);
                const int wcc = ok ? wc : 0;
                float4 v = *(const float4*)(xr + wcc * 12);
                if (!ok) { v.x = 0.f; v.y = 0.f; v.z = 0.f; v.w = 0.f; }
                const int olo = (rr - 4 < 0) ? 0 : rr - 4;   // dh = rr - o in 0..4
                const int ohi = (rr > 7) ? 7 : rr;
#pragma unroll
                for (int o = olo; o <= ohi; ++o) {
                    const float g = wgt[(rr - o) * 5 + dw];
                    acc[o][0] = fmaf(g, v.x, acc[o][0]);
                    acc[o][1] = fmaf(g, v.y, acc[o][1]);
                    acc[o][2] = fmaf(g, v.z, acc[o][2]);
                    acc[o][3] = fmaf(g, v.w, acc[o][3]);
                }
            }
        }
    }

    float* pb = part + (size_t)q * PART_SZ;
#pragma unroll
    for (int o = 0; o < 8; ++o) {
        const int h = htb + o;
        float4 st; st.x = acc[o][0]; st.y = acc[o][1]; st.z = acc[o][2]; st.w = acc[o][3];
        *(float4*)(pb + (size_t)((b * 64 + h) * 64 + w) * 12 + tg * 4) = st;
    }
}

// ---------------------------------------------------------------------------
// K3: sum the 16 channel-group partials, softmax over t (12), write p to ws.
__global__ __launch_bounds__(256) void k_soft(const float* __restrict__ part,
                                              float* __restrict__ p) {
    const int idx = blockIdx.x * 256 + threadIdx.x;  // (b,h,w) flat, 0..32767
    if (idx >= 32768) return;
    float v[12];
#pragma unroll
    for (int t = 0; t < 12; ++t) v[t] = 0.f;
#pragma unroll
    for (int qg = 0; qg < 16; ++qg) {
        const float* pp = part + (size_t)qg * PART_SZ + (size_t)idx * 12;
        float4 t0 = *(const float4*)(pp);
        float4 t1 = *(const float4*)(pp + 4);
        float4 t2 = *(const float4*)(pp + 8);
        v[0] += t0.x; v[1] += t0.y; v[2]  += t0.z; v[3]  += t0.w;
        v[4] += t1.x; v[5] += t1.y; v[6]  += t1.z; v[7]  += t1.w;
        v[8] += t2.x; v[9] += t2.y; v[10] += t2.z; v[11] += t2.w;
    }
    float m = v[0];
#pragma unroll
    for (int t = 1; t < 12; ++t) m = fmaxf(m, v[t]);
    float s = 0.f;
#pragma unroll
    for (int t = 0; t < 12; ++t) { v[t] = __expf(v[t] - m); s += v[t]; }
    const float inv = 1.f / s;
#pragma unroll
    for (int t = 0; t < 12; ++t) v[t] *= inv;
    float* op = p + (size_t)idx * 12;
    float4 s0; s0.x = v[0]; s0.y = v[1]; s0.z = v[2];  s0.w = v[3];
    float4 s1; s1.x = v[4]; s1.y = v[5]; s1.z = v[6];  s1.w = v[7];
    float4 s2; s2.x = v[8]; s2.y = v[9]; s2.z = v[10]; s2.w = v[11];
    *(float4*)(op)     = s0;
    *(float4*)(op + 4) = s1;
    *(float4*)(op + 8) = s2;
}

// ---------------------------------------------------------------------------
// K4: out[b,c,h,w,s] = W1v · (sum_t p_t * x[:,t]) + b1v, broadcast over s.
// One thread per (b,h,w): xbar[64] in registers; W1v rows via uniform scalar
// loads (SGPR operand in the FMA). 512 blocks * 64 threads.
__global__ __launch_bounds__(64) void k_out(const float* __restrict__ x,
                                            const float* __restrict__ w1,
                                            const float* __restrict__ b1,
                                            const float* __restrict__ p,
                                            float* __restrict__ out) {
    const int b = blockIdx.x >> 6;
    const int h = blockIdx.x & 63;
    const int w = threadIdx.x;   // 0..63

    const float* pp = p + (size_t)((b * 64 + h) * 64 + w) * 12;
    float pv[12];
    {
        float4 t0 = *(const float4*)(pp);
        float4 t1 = *(const float4*)(pp + 4);
        float4 t2 = *(const float4*)(pp + 8);
        pv[0] = t0.x; pv[1] = t0.y; pv[2]  = t0.z; pv[3]  = t0.w;
        pv[4] = t1.x; pv[5] = t1.y; pv[6]  = t1.z; pv[7]  = t1.w;
        pv[8] = t2.x; pv[9] = t2.y; pv[10] = t2.z; pv[11] = t2.w;
    }

    float xbar[64];
    const float* xb0 = x + ((size_t)(b * 64) * 64 + h) * 768 + w * 12;
#pragma unroll
    for (int c = 0; c < 64; ++c) {
        const float* xp = xb0 + (size_t)c * 49152;
        float4 u0 = *(const float4*)(xp);
        float4 u1 = *(const float4*)(xp + 4);
        float4 u2 = *(const float4*)(xp + 8);
        float s = 0.f;
        s = fmaf(pv[0], u0.x, s);  s = fmaf(pv[1], u0.y, s);
        s = fmaf(pv[2], u0.z, s);  s = fmaf(pv[3], u0.w, s);
        s = fmaf(pv[4], u1.x, s);  s = fmaf(pv[5], u1.y, s);
        s = fmaf(pv[6], u1.z, s);  s = fmaf(pv[7], u1.w, s);
        s = fmaf(pv[8], u2.x, s);  s = fmaf(pv[9], u2.y, s);
        s = fmaf(pv[10], u2.z, s); s = fmaf(pv[11], u2.w, s);
        xbar[c] = s;
    }

    const float* w1v = w1 + 128 * 64;
    for (int co = 0; co < 64; ++co) {
        float s = b1[128 + co];
#pragma unroll
        for (int c2 = 0; c2 < 64; ++c2)
            s = fmaf(w1v[co * 64 + c2], xbar[c2], s);
        float4 f; f.x = s; f.y = s; f.z = s; f.w = s;
        float* op = out + ((size_t)(b * 64 + co) * 4096 + h * 64 + w) * 12;
        *(float4*)(op)     = f;
        *(float4*)(op + 4) = f;
        *(float4*)(op + 8) = f;
    }
}

// ---------------------------------------------------------------------------
extern "C" void kernel_launch(void* const* d_in, const int* in_sizes, int n_in,
                              void* d_out, int out_size, void* d_ws, size_t ws_size,
                              hipStream_t stream) {
    const float* x  = (const float*)d_in[0];
    const float* w1 = (const float*)d_in[1];
    const float* b1 = (const float*)d_in[2];
    const float* w2 = (const float*)d_in[3];
    // d_in[4] = b2: constant across the softmax axis -> cancels, unused.

    float* outp = (float*)d_out;
    float* weff = outp + WEFF_OFF;   // scratch inside d_out (overwritten last)
    float* part = outp + PART_OFF;   // scratch inside d_out
    float* p    = (float*)d_ws;      // 1.57 MB

    hipLaunchKernelGGL(k_prep, dim3(7),    dim3(256), 0, stream, w1, w2, weff);
    hipLaunchKernelGGL(k_conv, dim3(1536), dim3(128), 0, stream, x, weff, part);
    hipLaunchKernelGGL(k_soft, dim3(128),  dim3(256), 0, stream, part, p);
    hipLaunchKernelGGL(k_out,  dim3(512),  dim3(64),  0, stream, x, w1, b1, p, outp);
}

// Round 2
// 99.618 us; speedup vs baseline: 1.5409x; 1.5409x over previous
//
#include <hip/hip_runtime.h>
#include <hip/hip_bf16.h>

// Problem dims
#define X_B 8
#define X_C 64
#define X_H 64
#define X_W 64
#define X_S 12
// x index: (((b*64 + c)*64 + h)*64 + w)*12 + t
// h-row stride = 768 floats, channel stride = 49152 floats

// Scratch layout inside d_out (floats) — consumed before final output overwrites it:
//   [0,1600)                : Weff[c'*25 + tap]
//   [4096, 4096+16*393216)  : partial A_k per channel-group q, layout ((b*64+h)*64+w)*12+t
#define WEFF_OFF 0
#define PART_OFF 4096
#define PART_SZ  393216   // 8*64*64*12
// d_ws: p[((b*64+h)*64+w)*12 + t]  (393216 floats = 1.57 MB)

// ---------------------------------------------------------------------------
// K1: fold 1x1-conv (key half of w1) into the 5x5 conv weights.
// Weff[c'][tap] = sum_c w2[0, 64+c, dh, dw] * w1[64+c, c']
__global__ __launch_bounds__(256) void k_prep(const float* __restrict__ w1,
                                              const float* __restrict__ w2,
                                              float* __restrict__ weff) {
    int idx = blockIdx.x * 256 + threadIdx.x;
    if (idx >= 64 * 25) return;
    int cp = idx / 25, tap = idx % 25;
    float s = 0.f;
    for (int c = 0; c < 64; ++c)
        s = fmaf(w2[(64 + c) * 25 + tap], w1[(64 + c) * 64 + cp], s);
    weff[cp * 25 + tap] = s;
}

// ---------------------------------------------------------------------------
// K2: direct fused 5x5x64 conv on x producing partial A_k (bias dropped: it is
// t-independent and cancels in the softmax over t).
// Grid: 1536 blocks = 8 b * 4 h-strips * 3 t-groups * 16 channel-groups.
// Block: 128 threads = 64 w-lanes * 2 row-halves; each thread owns 8 output
// rows * 4 t -> 32 accumulators; loads are float4 (4 t), lane=w => coalesced.
__global__ __launch_bounds__(128) void k_conv(const float* __restrict__ x,
                                              const float* __restrict__ weff,
                                              float* __restrict__ part) {
    const int bid   = blockIdx.x;
    const int b     = bid & 7;
    const int strip = (bid >> 3) & 3;
    const int tg    = (bid >> 5) % 3;
    const int q     = bid / 96;            // 0..15 -> channels q*4 .. q*4+3

    const int w   = threadIdx.x & 63;
    const int hq  = threadIdx.x >> 6;      // 0..1
    const int htb = strip * 16 + hq * 8;   // this thread's output rows htb..htb+7

    float acc[8][4];
#pragma unroll
    for (int o = 0; o < 8; ++o)
#pragma unroll
        for (int j = 0; j < 4; ++j) acc[o][j] = 0.f;

    for (int ci = 0; ci < 4; ++ci) {
        const int c = q * 4 + ci;
        const float* wp = weff + c * 25;   // uniform -> scalar loads
        float wgt[25];
#pragma unroll
        for (int k = 0; k < 25; ++k) wgt[k] = wp[k];

        const float* xc = x + (size_t)(b * 64 + c) * 49152 + tg * 4;
#pragma unroll
        for (int rr = 0; rr < 12; ++rr) {          // input rows htb-2 .. htb+9
            const int r = htb - 2 + rr;
            if (r < 0 || r >= 64) continue;        // wave-uniform skip
            const float* xr = xc + r * 768;
#pragma unroll
            for (int dw = 0; dw < 5; ++dw) {
                const int wc = w + dw - 2;
                const bool ok = ((unsigned)wc < 64u);
                const int wcc = ok ? wc : 0;
                float4 v = *(const float4*)(xr + wcc * 12);
                if (!ok) { v.x = 0.f; v.y = 0.f; v.z = 0.f; v.w = 0.f; }
                const int olo = (rr - 4 < 0) ? 0 : rr - 4;   // dh = rr - o in 0..4
                const int ohi = (rr > 7) ? 7 : rr;
#pragma unroll
                for (int o = olo; o <= ohi; ++o) {
                    const float g = wgt[(rr - o) * 5 + dw];
                    acc[o][0] = fmaf(g, v.x, acc[o][0]);
                    acc[o][1] = fmaf(g, v.y, acc[o][1]);
                    acc[o][2] = fmaf(g, v.z, acc[o][2]);
                    acc[o][3] = fmaf(g, v.w, acc[o][3]);
                }
            }
        }
    }

    float* pb = part + (size_t)q * PART_SZ;
#pragma unroll
    for (int o = 0; o < 8; ++o) {
        const int h = htb + o;
        float4 st; st.x = acc[o][0]; st.y = acc[o][1]; st.z = acc[o][2]; st.w = acc[o][3];
        *(float4*)(pb + (size_t)((b * 64 + h) * 64 + w) * 12 + tg * 4) = st;
    }
}

// ---------------------------------------------------------------------------
// K3: sum the 16 channel-group partials, softmax over t (12), write p to ws.
__global__ __launch_bounds__(256) void k_soft(const float* __restrict__ part,
                                              float* __restrict__ p) {
    const int idx = blockIdx.x * 256 + threadIdx.x;  // (b,h,w) flat, 0..32767
    if (idx >= 32768) return;
    float v[12];
#pragma unroll
    for (int t = 0; t < 12; ++t) v[t] = 0.f;
#pragma unroll
    for (int qg = 0; qg < 16; ++qg) {
        const float* pp = part + (size_t)qg * PART_SZ + (size_t)idx * 12;
        float4 t0 = *(const float4*)(pp);
        float4 t1 = *(const float4*)(pp + 4);
        float4 t2 = *(const float4*)(pp + 8);
        v[0] += t0.x; v[1] += t0.y; v[2]  += t0.z; v[3]  += t0.w;
        v[4] += t1.x; v[5] += t1.y; v[6]  += t1.z; v[7]  += t1.w;
        v[8] += t2.x; v[9] += t2.y; v[10] += t2.z; v[11] += t2.w;
    }
    float m = v[0];
#pragma unroll
    for (int t = 1; t < 12; ++t) m = fmaxf(m, v[t]);
    float s = 0.f;
#pragma unroll
    for (int t = 0; t < 12; ++t) { v[t] = __expf(v[t] - m); s += v[t]; }
    const float inv = 1.f / s;
#pragma unroll
    for (int t = 0; t < 12; ++t) v[t] *= inv;
    float* op = p + (size_t)idx * 12;
    float4 s0; s0.x = v[0]; s0.y = v[1]; s0.z = v[2];  s0.w = v[3];
    float4 s1; s1.x = v[4]; s1.y = v[5]; s1.z = v[6];  s1.w = v[7];
    float4 s2; s2.x = v[8]; s2.y = v[9]; s2.z = v[10]; s2.w = v[11];
    *(float4*)(op)     = s0;
    *(float4*)(op + 4) = s1;
    *(float4*)(op + 8) = s2;
}

// ---------------------------------------------------------------------------
// K4 (v2): out[b,c,h,w,s] = W1v · (sum_t p_t * x[:,t]) + b1v, broadcast over s.
// One block per (b,h): 512 threads = 64 w-lanes * 8 channel-groups.
// Phase 1: thread (w,cg) computes xbar for channels cg*8..cg*8+7 -> LDS[w][65-pad].
// Phase 2: thread (w,cg) does the 8-row matvec with wave-uniform w1v operands.
// 512 blocks * 8 waves = 4096 waves = 16 waves/CU (was 2 waves/CU in v1).
__global__ __launch_bounds__(512) void k_out(const float* __restrict__ x,
                                             const float* __restrict__ w1,
                                             const float* __restrict__ b1,
                                             const float* __restrict__ p,
                                             float* __restrict__ out) {
    __shared__ float lds[64 * 65];   // [w][c], padded -> bank (w+c)%32, conflict-free

    const int b  = blockIdx.x >> 6;
    const int h  = blockIdx.x & 63;
    const int w  = threadIdx.x & 63;
    const int cg = threadIdx.x >> 6;     // 0..7

    // per-(b,h,w) softmax weights (8 threads share one address -> broadcast)
    const float* pp = p + (size_t)((b * 64 + h) * 64 + w) * 12;
    float pv[12];
    {
        float4 t0 = *(const float4*)(pp);
        float4 t1 = *(const float4*)(pp + 4);
        float4 t2 = *(const float4*)(pp + 8);
        pv[0] = t0.x; pv[1] = t0.y; pv[2]  = t0.z; pv[3]  = t0.w;
        pv[4] = t1.x; pv[5] = t1.y; pv[6]  = t1.z; pv[7]  = t1.w;
        pv[8] = t2.x; pv[9] = t2.y; pv[10] = t2.z; pv[11] = t2.w;
    }

    // Phase 1: xbar for this thread's 8 channels
    const float* xb0 = x + ((size_t)(b * 64 + cg * 8) * 64 + h) * 768 + w * 12;
#pragma unroll
    for (int j = 0; j < 8; ++j) {
        const float* xp = xb0 + (size_t)j * 49152;
        float4 u0 = *(const float4*)(xp);
        float4 u1 = *(const float4*)(xp + 4);
        float4 u2 = *(const float4*)(xp + 8);
        float s = 0.f;
        s = fmaf(pv[0], u0.x, s);  s = fmaf(pv[1], u0.y, s);
        s = fmaf(pv[2], u0.z, s);  s = fmaf(pv[3], u0.w, s);
        s = fmaf(pv[4], u1.x, s);  s = fmaf(pv[5], u1.y, s);
        s = fmaf(pv[6], u1.z, s);  s = fmaf(pv[7], u1.w, s);
        s = fmaf(pv[8], u2.x, s);  s = fmaf(pv[9], u2.y, s);
        s = fmaf(pv[10], u2.z, s); s = fmaf(pv[11], u2.w, s);
        lds[w * 65 + cg * 8 + j] = s;
    }
    __syncthreads();

    // Phase 2: 8 output channels per thread; w1v loads are wave-uniform (scalar)
    const float* w1v = w1 + 128 * 64 + cg * 8 * 64;
    float acc[8];
#pragma unroll
    for (int j = 0; j < 8; ++j) acc[j] = b1[128 + cg * 8 + j];
    for (int c2 = 0; c2 < 64; ++c2) {
        const float xv = lds[w * 65 + c2];
#pragma unroll
        for (int j = 0; j < 8; ++j)
            acc[j] = fmaf(w1v[j * 64 + c2], xv, acc[j]);
    }

#pragma unroll
    for (int j = 0; j < 8; ++j) {
        const int co = cg * 8 + j;
        float4 f; f.x = acc[j]; f.y = acc[j]; f.z = acc[j]; f.w = acc[j];
        float* op = out + ((size_t)(b * 64 + co) * 4096 + h * 64 + w) * 12;
        *(float4*)(op)     = f;
        *(float4*)(op + 4) = f;
        *(float4*)(op + 8) = f;
    }
}

// ---------------------------------------------------------------------------
extern "C" void kernel_launch(void* const* d_in, const int* in_sizes, int n_in,
                              void* d_out, int out_size, void* d_ws, size_t ws_size,
                              hipStream_t stream) {
    const float* x  = (const float*)d_in[0];
    const float* w1 = (const float*)d_in[1];
    const float* b1 = (const float*)d_in[2];
    const float* w2 = (const float*)d_in[3];
    // d_in[4] = b2: constant across the softmax axis -> cancels, unused.

    float* outp = (float*)d_out;
    float* weff = outp + WEFF_OFF;   // scratch inside d_out (overwritten last)
    float* part = outp + PART_OFF;   // scratch inside d_out
    float* p    = (float*)d_ws;      // 1.57 MB

    hipLaunchKernelGGL(k_prep, dim3(7),    dim3(256), 0, stream, w1, w2, weff);
    hipLaunchKernelGGL(k_conv, dim3(1536), dim3(128), 0, stream, x, weff, part);
    hipLaunchKernelGGL(k_soft, dim3(128),  dim3(256), 0, stream, part, p);
    hipLaunchKernelGGL(k_out,  dim3(512),  dim3(512), 0, stream, x, w1, b1, p, outp);
}